// Round 7
// baseline (242.205 us; speedup 1.0000x reference)
//
#include <hip/hip_runtime.h>
#include <hip/hip_bf16.h>
#include <stdint.h>

#define B_   4096
#define IN_  1024
#define H_   1024
#define OUT_ 1024

typedef __attribute__((ext_vector_type(8)))  short short8;
typedef __attribute__((ext_vector_type(16))) float floatx16;

// ---------- async global->LDS (16B per lane; LDS base wave-uniform, HW adds lane*16) ----------
__device__ static inline void gload_lds16(const void* g, void* l) {
    __builtin_amdgcn_global_load_lds(
        (const __attribute__((address_space(1))) unsigned int*)g,
        (__attribute__((address_space(3))) unsigned int*)l,
        16, 0, 0);
}

__device__ static inline float sigmoidf_(float x) { return 1.0f / (1.0f + __expf(-x)); }
__device__ static inline float tanhf_(float x)    { return 1.0f - 2.0f / (1.0f + __expf(2.0f * x)); }

// ---------- merged conversion kernel — R10: grid-stride, 8 floats/thread/pass ----------
// R9 post-mortem: pipeline budget has ~110 us unexplained outside the gate GEMM; the
// 17408-block cvt (1 KB of loads per block) is the prime launch-overhead suspect.
// R10: 2048 blocks x 256 threads, grid-stride over 8-element granules:
// 2 x float4 load -> 8 x cvt -> one 16B store. 8.5x fewer blocks, half the stores.
// Granule map (granule = 8 consecutive outputs; 8 | 1024 so never splits a source):
//   [0, 1048576):        xh[b][c]  b=g>>8, c8=(g&255)*8   (c<1024 from x, else h)
//   [1048576, 2097152):  Wc gate-interleaved rows, same n-mapping as before
//   [2097152, 2228224):  Wob flat
struct Ptrs8 { const float* p[8]; };

__global__ __launch_bounds__(256) void cvt_all_kernel(
        const float* __restrict__ x, const float* __restrict__ h,
        Ptrs8 ptrs, const float* __restrict__ wout,
        __hip_bfloat16* __restrict__ xh,
        __hip_bfloat16* __restrict__ Wc,
        __hip_bfloat16* __restrict__ Wob) {
    const int nth = gridDim.x * blockDim.x;
    for (int g = blockIdx.x * blockDim.x + threadIdx.x; g < 2228224; g += nth) {
        const float* src;
        __hip_bfloat16* dst;
        if (g < 1048576) {
            int b  = g >> 8;                 // 256 granules per 2048-wide row
            int c8 = (g & 255) * 8;
            src = (c8 < IN_) ? (x + (size_t)b * IN_ + c8)
                             : (h + (size_t)b * H_ + (c8 - IN_));
            dst = xh + (size_t)b * 2048 + c8;
        } else if (g < 2097152) {
            int gg = g - 1048576;
            int n  = gg >> 8;
            int c8 = (gg & 255) * 8;
            int gate = (n >> 5) & 3;
            int hh   = ((n >> 7) << 5) + (n & 31);
            src = (c8 < 1024) ? (ptrs.p[2 * gate]     + (size_t)hh * 1024 + c8)
                              : (ptrs.p[2 * gate + 1] + (size_t)hh * 1024 + (c8 - 1024));
            dst = Wc + (size_t)n * 2048 + c8;
        } else {
            int gg = g - 2097152;
            src = wout + (size_t)gg * 8;
            dst = Wob + (size_t)gg * 8;
        }
        float4 v0 = *(const float4*)src;
        float4 v1 = *(const float4*)(src + 4);
        __hip_bfloat16 tmp[8];
        tmp[0] = __float2bfloat16(v0.x);
        tmp[1] = __float2bfloat16(v0.y);
        tmp[2] = __float2bfloat16(v0.z);
        tmp[3] = __float2bfloat16(v0.w);
        tmp[4] = __float2bfloat16(v1.x);
        tmp[5] = __float2bfloat16(v1.y);
        tmp[6] = __float2bfloat16(v1.z);
        tmp[7] = __float2bfloat16(v1.w);
        *(uint4*)dst = *(const uint4*)tmp;
    }
}

// ---------- gate GEMM + fused LSTM epilogue — R8 (measured best: 86.2 us) ----------
// Revert from R9 (intra-wave ping-pong regressed to 119 us: sched_barrier(0) pinning
// defeated the compiler's counted-lgkmcnt scheduling, m141-style).
// R8 structure: 2 barriers + counted vmcnt(8) per K-tile, free-running 4-phase compute.
__global__ __launch_bounds__(512, 2) void gemm_gate_fused(
    const __hip_bfloat16* __restrict__ A,
    const __hip_bfloat16* __restrict__ Bm,
    const float* __restrict__ cell,
    const float* __restrict__ bxf, const float* __restrict__ bxi,
    const float* __restrict__ bxo, const float* __restrict__ bxg,
    float* __restrict__ new_hidden, float* __restrict__ new_cell,
    __hip_bfloat16* __restrict__ hb)
{
    constexpr int K = 2048;

    // A/B x double buffer, 4 distinct 32 KB objects = 128 KB, 1 block/CU, 8 waves.
    __shared__ short sA0[16384];
    __shared__ short sB0[16384];
    __shared__ short sA1[16384];
    __shared__ short sB1[16384];

    const int tid  = threadIdx.x;
    const int lane = tid & 63;
    const int wv   = tid >> 6;     // 0..7
    const int wr   = wv >> 1;      // 0..3 (row band, 64 rows)
    const int wc   = wv & 1;       // 0..1 (col band, 128 cols)

    // 256 blocks = 1/CU. XCD swizzle: xcd owns n-tiles [xcd*2, xcd*2+2).
    const int bid    = blockIdx.x;
    const int xcd    = bid & 7;
    const int loc    = bid >> 3;               // 0..31
    const int n_tile = xcd * 2 + (loc & 1);    // 0..15
    const int m_tile = loc >> 1;               // 0..15
    const int m0 = m_tile * 256;
    const int n0 = n_tile * 256;

    // staging gather: thread tid fills LDS slot tid*16 within each 8KB (64-row) issue;
    // row = s*64 + tid/8, stored chunk = tid%8 -> fetch global chunk (tid%8)^(row&7)
    const int srow   = tid >> 3;               // 0..63
    const int schunk = tid & 7;
    const int scg    = schunk ^ (srow & 7);
    const __hip_bfloat16* Ag = A  + (size_t)(m0 + srow) * K + scg * 8;
    const __hip_bfloat16* Bg = Bm + (size_t)(n0 + srow) * K + scg * 8;
    const int wvoff = wv * 1024;               // gload_lds LDS base is wave-uniform

    const int fr    = lane & 31;
    const int khalf = lane >> 5;
    const int sw    = fr & 7;

    // loop-invariant LDS read byte offsets (within each 32 KB buffer)
    int offA[2], offB[4];
    #pragma unroll
    for (int i = 0; i < 2; ++i) offA[i] = (wr * 64 + i * 32 + fr) * 128;
    #pragma unroll
    for (int j = 0; j < 4; ++j) offB[j] = (wc * 128 + j * 32 + fr) * 128;

    floatx16 acc[2][4] = {};                   // [row half][gate]

    // ---- prologue: stage tile 0 into buffers 0. The t=0 body's vmcnt(8)
    // (after issuing tile 1's 8 loads) waits exactly for these 8. ----
    #pragma unroll
    for (int s = 0; s < 4; ++s)
        gload_lds16(Ag + (size_t)(s * 64) * K, (char*)sA0 + s * 8192 + wvoff);
    #pragma unroll
    for (int s = 0; s < 4; ++s)
        gload_lds16(Bg + (size_t)(s * 64) * K, (char*)sB0 + s * 8192 + wvoff);

#define TILE_BODY(RA, RB, WA, WB, tnext, DO_STAGE)                                        \
    {                                                                                     \
        /* (1) everyone finished READING the W-buffers (previous tile) */                 \
        __builtin_amdgcn_s_barrier();                                                     \
        if (DO_STAGE) {                                                                   \
            const __hip_bfloat16* Agt = Ag + (size_t)(tnext) * 64;                        \
            const __hip_bfloat16* Bgt = Bg + (size_t)(tnext) * 64;                        \
            _Pragma("unroll")                                                             \
            for (int s = 0; s < 4; ++s)                                                   \
                gload_lds16(Agt + (size_t)(s * 64) * K, (char*)(WA) + s * 8192 + wvoff);  \
            _Pragma("unroll")                                                             \
            for (int s = 0; s < 4; ++s)                                                   \
                gload_lds16(Bgt + (size_t)(s * 64) * K, (char*)(WB) + s * 8192 + wvoff);  \
            /* counted: 8 oldest (= R-buffers' loads) done; 8 new stay in flight */       \
            asm volatile("s_waitcnt vmcnt(8)" ::: "memory");                              \
        } else {                                                                          \
            asm volatile("s_waitcnt vmcnt(0)" ::: "memory");                              \
        }                                                                                 \
        /* (2) all waves' R-buffer loads complete -> fully staged */                      \
        __builtin_amdgcn_s_barrier();                                                     \
        __builtin_amdgcn_sched_barrier(0);                                                \
        /* free-running phases: no barriers; waves drift -> LDS/MFMA pipes overlap */     \
        _Pragma("unroll")                                                                 \
        for (int kk = 0; kk < 4; ++kk) {                                                  \
            const int co = ((kk * 2 + khalf) ^ sw) * 16;                                  \
            short8 af[2], bfr[4];                                                         \
            _Pragma("unroll")                                                             \
            for (int i = 0; i < 2; ++i)                                                   \
                af[i]  = *(const short8*)((const char*)(RA) + offA[i] + co);              \
            _Pragma("unroll")                                                             \
            for (int j = 0; j < 4; ++j)                                                   \
                bfr[j] = *(const short8*)((const char*)(RB) + offB[j] + co);              \
            __builtin_amdgcn_s_setprio(1);                                                \
            _Pragma("unroll")                                                             \
            for (int i = 0; i < 2; ++i)                                                   \
                _Pragma("unroll")                                                         \
                for (int j = 0; j < 4; ++j)                                               \
                    acc[i][j] = __builtin_amdgcn_mfma_f32_32x32x16_bf16(                  \
                        af[i], bfr[j], acc[i][j], 0, 0, 0);                               \
            __builtin_amdgcn_s_setprio(0);                                                \
        }                                                                                 \
    }

    #pragma unroll 1
    for (int t2 = 0; t2 < 16; ++t2) {
        TILE_BODY(sA0, sB0, sA1, sB1, 2 * t2 + 1, true);
        TILE_BODY(sA1, sB1, sA0, sB0, 2 * t2 + 2, (t2 < 15));
    }
#undef TILE_BODY

    // fused LSTM epilogue.
    // C/D layout (32x32): col = lane&31, row = (reg&3) + 8*(reg>>2) + 4*(lane>>5).
    // Wave's 128-col band = one gate-interleave period -> j == gate, lane owns all 4 gates.
    const int h  = ((n0 + wc * 128) >> 2) + fr;
    const float bfb = bxf[h];
    const float bib = bxi[h];
    const float bob = bxo[h];
    const float bgb = bxg[h];

    #pragma unroll
    for (int i = 0; i < 2; ++i) {
        const int row_base = m0 + wr * 64 + i * 32 + 4 * khalf;
        #pragma unroll
        for (int reg = 0; reg < 16; ++reg) {
            const int row = row_base + (reg & 3) + 8 * (reg >> 2);
            const size_t off = (size_t)row * H_ + h;
            const float f  = sigmoidf_(acc[i][0][reg] + bfb);
            const float ii = sigmoidf_(acc[i][1][reg] + bib);
            const float o  = sigmoidf_(acc[i][2][reg] + bob);
            const float g  = tanhf_(acc[i][3][reg] + bgb);
            const float c  = f * cell[off] + ii * g;
            const float nh = o * tanhf_(c);
            new_cell[off]   = c;
            new_hidden[off] = nh;
            hb[off] = __float2bfloat16(nh);
        }
    }
}

// ---------- output GEMM (unchanged R3 measured-best config): C = A * B^T + bias ----------
__global__ __launch_bounds__(256, 2) void gemm_out(
    const __hip_bfloat16* __restrict__ A,
    const __hip_bfloat16* __restrict__ Bm,
    float* __restrict__ C,
    const float* __restrict__ bias)
{
    constexpr int BK = 64;
    constexpr int K  = 1024;
    constexpr int N  = 1024;

    __shared__ __hip_bfloat16 ldsA[128 * BK];  // 16 KB
    __shared__ __hip_bfloat16 ldsB[64 * BK];   //  8 KB

    const int tid  = threadIdx.x;
    const int lane = tid & 63;
    const int wv   = tid >> 6;

    const int bid    = blockIdx.x;
    const int xcd    = bid & 7;
    const int loc    = bid >> 3;               // 0..63
    const int n_tile = xcd * 2 + (loc & 1);    // 0..15
    const int m_tile = loc >> 1;               // 0..31
    const int m0 = m_tile * 128;
    const int n0 = n_tile * 64;

    const int srow   = tid >> 3;
    const int schunk = tid & 7;
    const int scg    = schunk ^ (srow & 7);
    const __hip_bfloat16* Ag = A  + (size_t)(m0 + srow) * K + scg * 8;
    const __hip_bfloat16* Bg = Bm + (size_t)(n0 + srow) * K + scg * 8;
    char* lA = (char*)ldsA + wv * 1024;
    char* lB = (char*)ldsB + wv * 1024;

    const int wrow  = wv * 32;
    const int fr    = lane & 31;
    const int khalf = lane >> 5;

    floatx16 acc[2] = {};

    for (int k0 = 0; k0 < K; k0 += BK) {
        #pragma unroll
        for (int s = 0; s < 4; ++s)
            gload_lds16(Ag + (size_t)(s * 32) * K + k0, lA + s * 4096);
        #pragma unroll
        for (int s = 0; s < 2; ++s)
            gload_lds16(Bg + (size_t)(s * 32) * K + k0, lB + s * 4096);
        __syncthreads();

        #pragma unroll
        for (int kk = 0; kk < 4; ++kk) {
            const int cg = kk * 2 + khalf;
            const int ra = wrow + fr;
            short8 af = *(const short8*)((const char*)ldsA + ra * 128 + ((cg ^ (ra & 7)) * 16));
            short8 bf[2];
            #pragma unroll
            for (int j = 0; j < 2; ++j) {
                const int r = j * 32 + fr;
                bf[j] = *(const short8*)((const char*)ldsB + r * 128 + ((cg ^ (r & 7)) * 16));
            }
            #pragma unroll
            for (int j = 0; j < 2; ++j)
                acc[j] = __builtin_amdgcn_mfma_f32_32x32x16_bf16(af, bf[j], acc[j], 0, 0, 0);
        }
        __syncthreads();
    }

    #pragma unroll
    for (int j = 0; j < 2; ++j) {
        const int col = n0 + j * 32 + fr;
        const float bb = bias[col];
        #pragma unroll
        for (int reg = 0; reg < 16; ++reg) {
            const int row = m0 + wrow + 4 * khalf + (reg & 3) + 8 * (reg >> 2);
            C[(size_t)row * N + col] = acc[j][reg] + bb;
        }
    }
}

// ---------- launch ----------
extern "C" void kernel_launch(void* const* d_in, const int* in_sizes, int n_in,
                              void* d_out, int out_size, void* d_ws, size_t ws_size,
                              hipStream_t stream) {
    const float* input_vec  = (const float*)d_in[0];
    const float* hidden_vec = (const float*)d_in[1];
    const float* cell_vec   = (const float*)d_in[2];
    const float* Wx_f = (const float*)d_in[3];
    const float* bx_f = (const float*)d_in[4];
    const float* Wh_f = (const float*)d_in[5];
    const float* Wx_i = (const float*)d_in[6];
    const float* bx_i = (const float*)d_in[7];
    const float* Wh_i = (const float*)d_in[8];
    const float* Wx_o = (const float*)d_in[9];
    const float* bx_o = (const float*)d_in[10];
    const float* Wh_o = (const float*)d_in[11];
    const float* Wx_g = (const float*)d_in[12];
    const float* bx_g = (const float*)d_in[13];
    const float* Wh_g = (const float*)d_in[14];
    const float* W_out = (const float*)d_in[15];
    const float* b_out = (const float*)d_in[16];

    char* ws = (char*)d_ws;
    __hip_bfloat16* xh  = (__hip_bfloat16*)(ws);                        // 16 MB [4096][2048]
    __hip_bfloat16* Wc  = (__hip_bfloat16*)(ws + (16ull << 20));        // 16 MB [4096][2048]
    __hip_bfloat16* Wob = (__hip_bfloat16*)(ws + (32ull << 20));        //  2 MB [1024][1024]
    __hip_bfloat16* hb  = (__hip_bfloat16*)(ws + (34ull << 20));        //  8 MB [4096][1024]

    float* new_hidden = (float*)d_out;
    float* new_cell   = new_hidden + (size_t)B_ * H_;
    float* out_vec    = new_cell + (size_t)B_ * H_;

    Ptrs8 p;
    p.p[0] = Wx_f; p.p[1] = Wh_f; p.p[2] = Wx_i; p.p[3] = Wh_i;
    p.p[4] = Wx_o; p.p[5] = Wh_o; p.p[6] = Wx_g; p.p[7] = Wh_g;
    cvt_all_kernel<<<2048, 256, 0, stream>>>(input_vec, hidden_vec, p, W_out, xh, Wc, Wob);

    // gates GEMM + fused gating: writes new_hidden, new_cell (fp32) and hb (bf16)
    gemm_gate_fused<<<256, 512, 0, stream>>>(
        xh, Wc, cell_vec, bx_f, bx_i, bx_o, bx_g, new_hidden, new_cell, hb);

    // output_vec = new_hidden @ W_out^T + b_out
    gemm_out<<<512, 256, 0, stream>>>(hb, Wob, out_vec, b_out);
}

// Round 8
// 240.751 us; speedup vs baseline: 1.0060x; 1.0060x over previous
//
#include <hip/hip_runtime.h>
#include <hip/hip_bf16.h>
#include <stdint.h>

#define B_   4096
#define IN_  1024
#define H_   1024
#define OUT_ 1024

typedef __attribute__((ext_vector_type(8)))  short short8;
typedef __attribute__((ext_vector_type(16))) float floatx16;

// ---------- async global->LDS (16B per lane; LDS base wave-uniform, HW adds lane*16) ----------
__device__ static inline void gload_lds16(const void* g, void* l) {
    __builtin_amdgcn_global_load_lds(
        (const __attribute__((address_space(1))) unsigned int*)g,
        (__attribute__((address_space(3))) unsigned int*)l,
        16, 0, 0);
}

__device__ static inline float sigmoidf_(float x) { return 1.0f / (1.0f + __expf(-x)); }
__device__ static inline float tanhf_(float x)    { return 1.0f - 2.0f / (1.0f + __expf(2.0f * x)); }

// ---------- merged conversion kernel (R10 grid-stride; shape-invariant ~BW floor) ----------
struct Ptrs8 { const float* p[8]; };

__global__ __launch_bounds__(256) void cvt_all_kernel(
        const float* __restrict__ x, const float* __restrict__ h,
        Ptrs8 ptrs, const float* __restrict__ wout,
        __hip_bfloat16* __restrict__ xh,
        __hip_bfloat16* __restrict__ Wc,
        __hip_bfloat16* __restrict__ Wob) {
    const int nth = gridDim.x * blockDim.x;
    for (int g = blockIdx.x * blockDim.x + threadIdx.x; g < 2228224; g += nth) {
        const float* src;
        __hip_bfloat16* dst;
        if (g < 1048576) {
            int b  = g >> 8;                 // 256 granules per 2048-wide row
            int c8 = (g & 255) * 8;
            src = (c8 < IN_) ? (x + (size_t)b * IN_ + c8)
                             : (h + (size_t)b * H_ + (c8 - IN_));
            dst = xh + (size_t)b * 2048 + c8;
        } else if (g < 2097152) {
            int gg = g - 1048576;
            int n  = gg >> 8;
            int c8 = (gg & 255) * 8;
            int gate = (n >> 5) & 3;
            int hh   = ((n >> 7) << 5) + (n & 31);
            src = (c8 < 1024) ? (ptrs.p[2 * gate]     + (size_t)hh * 1024 + c8)
                              : (ptrs.p[2 * gate + 1] + (size_t)hh * 1024 + (c8 - 1024));
            dst = Wc + (size_t)n * 2048 + c8;
        } else {
            int gg = g - 2097152;
            src = wout + (size_t)gg * 8;
            dst = Wob + (size_t)gg * 8;
        }
        float4 v0 = *(const float4*)src;
        float4 v1 = *(const float4*)(src + 4);
        __hip_bfloat16 tmp[8];
        tmp[0] = __float2bfloat16(v0.x);
        tmp[1] = __float2bfloat16(v0.y);
        tmp[2] = __float2bfloat16(v0.z);
        tmp[3] = __float2bfloat16(v0.w);
        tmp[4] = __float2bfloat16(v1.x);
        tmp[5] = __float2bfloat16(v1.y);
        tmp[6] = __float2bfloat16(v1.z);
        tmp[7] = __float2bfloat16(v1.w);
        *(uint4*)dst = *(const uint4*)tmp;
    }
}

// ---------- gate GEMM + fused LSTM epilogue — R8 (measured best: 85.5 us) — FROZEN ----------
__global__ __launch_bounds__(512, 2) void gemm_gate_fused(
    const __hip_bfloat16* __restrict__ A,
    const __hip_bfloat16* __restrict__ Bm,
    const float* __restrict__ cell,
    const float* __restrict__ bxf, const float* __restrict__ bxi,
    const float* __restrict__ bxo, const float* __restrict__ bxg,
    float* __restrict__ new_hidden, float* __restrict__ new_cell,
    __hip_bfloat16* __restrict__ hb)
{
    constexpr int K = 2048;

    // A/B x double buffer, 4 distinct 32 KB objects = 128 KB, 1 block/CU, 8 waves.
    __shared__ short sA0[16384];
    __shared__ short sB0[16384];
    __shared__ short sA1[16384];
    __shared__ short sB1[16384];

    const int tid  = threadIdx.x;
    const int lane = tid & 63;
    const int wv   = tid >> 6;     // 0..7
    const int wr   = wv >> 1;      // 0..3 (row band, 64 rows)
    const int wc   = wv & 1;       // 0..1 (col band, 128 cols)

    // 256 blocks = 1/CU. XCD swizzle: xcd owns n-tiles [xcd*2, xcd*2+2).
    const int bid    = blockIdx.x;
    const int xcd    = bid & 7;
    const int loc    = bid >> 3;               // 0..31
    const int n_tile = xcd * 2 + (loc & 1);    // 0..15
    const int m_tile = loc >> 1;               // 0..15
    const int m0 = m_tile * 256;
    const int n0 = n_tile * 256;

    // staging gather: thread tid fills LDS slot tid*16 within each 8KB (64-row) issue;
    // row = s*64 + tid/8, stored chunk = tid%8 -> fetch global chunk (tid%8)^(row&7)
    const int srow   = tid >> 3;               // 0..63
    const int schunk = tid & 7;
    const int scg    = schunk ^ (srow & 7);
    const __hip_bfloat16* Ag = A  + (size_t)(m0 + srow) * K + scg * 8;
    const __hip_bfloat16* Bg = Bm + (size_t)(n0 + srow) * K + scg * 8;
    const int wvoff = wv * 1024;               // gload_lds LDS base is wave-uniform

    const int fr    = lane & 31;
    const int khalf = lane >> 5;
    const int sw    = fr & 7;

    // loop-invariant LDS read byte offsets (within each 32 KB buffer)
    int offA[2], offB[4];
    #pragma unroll
    for (int i = 0; i < 2; ++i) offA[i] = (wr * 64 + i * 32 + fr) * 128;
    #pragma unroll
    for (int j = 0; j < 4; ++j) offB[j] = (wc * 128 + j * 32 + fr) * 128;

    floatx16 acc[2][4] = {};                   // [row half][gate]

    // ---- prologue: stage tile 0 into buffers 0. The t=0 body's vmcnt(8)
    // (after issuing tile 1's 8 loads) waits exactly for these 8. ----
    #pragma unroll
    for (int s = 0; s < 4; ++s)
        gload_lds16(Ag + (size_t)(s * 64) * K, (char*)sA0 + s * 8192 + wvoff);
    #pragma unroll
    for (int s = 0; s < 4; ++s)
        gload_lds16(Bg + (size_t)(s * 64) * K, (char*)sB0 + s * 8192 + wvoff);

#define TILE_BODY(RA, RB, WA, WB, tnext, DO_STAGE)                                        \
    {                                                                                     \
        /* (1) everyone finished READING the W-buffers (previous tile) */                 \
        __builtin_amdgcn_s_barrier();                                                     \
        if (DO_STAGE) {                                                                   \
            const __hip_bfloat16* Agt = Ag + (size_t)(tnext) * 64;                        \
            const __hip_bfloat16* Bgt = Bg + (size_t)(tnext) * 64;                        \
            _Pragma("unroll")                                                             \
            for (int s = 0; s < 4; ++s)                                                   \
                gload_lds16(Agt + (size_t)(s * 64) * K, (char*)(WA) + s * 8192 + wvoff);  \
            _Pragma("unroll")                                                             \
            for (int s = 0; s < 4; ++s)                                                   \
                gload_lds16(Bgt + (size_t)(s * 64) * K, (char*)(WB) + s * 8192 + wvoff);  \
            /* counted: 8 oldest (= R-buffers' loads) done; 8 new stay in flight */       \
            asm volatile("s_waitcnt vmcnt(8)" ::: "memory");                              \
        } else {                                                                          \
            asm volatile("s_waitcnt vmcnt(0)" ::: "memory");                              \
        }                                                                                 \
        /* (2) all waves' R-buffer loads complete -> fully staged */                      \
        __builtin_amdgcn_s_barrier();                                                     \
        __builtin_amdgcn_sched_barrier(0);                                                \
        /* free-running phases: no barriers; waves drift -> LDS/MFMA pipes overlap */     \
        _Pragma("unroll")                                                                 \
        for (int kk = 0; kk < 4; ++kk) {                                                  \
            const int co = ((kk * 2 + khalf) ^ sw) * 16;                                  \
            short8 af[2], bfr[4];                                                         \
            _Pragma("unroll")                                                             \
            for (int i = 0; i < 2; ++i)                                                   \
                af[i]  = *(const short8*)((const char*)(RA) + offA[i] + co);              \
            _Pragma("unroll")                                                             \
            for (int j = 0; j < 4; ++j)                                                   \
                bfr[j] = *(const short8*)((const char*)(RB) + offB[j] + co);              \
            __builtin_amdgcn_s_setprio(1);                                                \
            _Pragma("unroll")                                                             \
            for (int i = 0; i < 2; ++i)                                                   \
                _Pragma("unroll")                                                         \
                for (int j = 0; j < 4; ++j)                                               \
                    acc[i][j] = __builtin_amdgcn_mfma_f32_32x32x16_bf16(                  \
                        af[i], bfr[j], acc[i][j], 0, 0, 0);                               \
            __builtin_amdgcn_s_setprio(0);                                                \
        }                                                                                 \
    }

    #pragma unroll 1
    for (int t2 = 0; t2 < 16; ++t2) {
        TILE_BODY(sA0, sB0, sA1, sB1, 2 * t2 + 1, true);
        TILE_BODY(sA1, sB1, sA0, sB0, 2 * t2 + 2, (t2 < 15));
    }
#undef TILE_BODY

    // fused LSTM epilogue.
    // C/D layout (32x32): col = lane&31, row = (reg&3) + 8*(reg>>2) + 4*(lane>>5).
    // Wave's 128-col band = one gate-interleave period -> j == gate, lane owns all 4 gates.
    const int h  = ((n0 + wc * 128) >> 2) + fr;
    const float bfb = bxf[h];
    const float bib = bxi[h];
    const float bob = bxo[h];
    const float bgb = bxg[h];

    #pragma unroll
    for (int i = 0; i < 2; ++i) {
        const int row_base = m0 + wr * 64 + i * 32 + 4 * khalf;
        #pragma unroll
        for (int reg = 0; reg < 16; ++reg) {
            const int row = row_base + (reg & 3) + 8 * (reg >> 2);
            const size_t off = (size_t)row * H_ + h;
            const float f  = sigmoidf_(acc[i][0][reg] + bfb);
            const float ii = sigmoidf_(acc[i][1][reg] + bib);
            const float o  = sigmoidf_(acc[i][2][reg] + bob);
            const float g  = tanhf_(acc[i][3][reg] + bgb);
            const float c  = f * cell[off] + ii * g;
            const float nh = o * tanhf_(c);
            new_cell[off]   = c;
            new_hidden[off] = nh;
            hb[off] = __float2bfloat16(nh);
        }
    }
}

// ---------- output GEMM — R11: R8-style counted-vmcnt pipeline (was __syncthreads drain) ----------
// Geometry unchanged (512 blocks, 128x64 tile, BK=64, 4 waves, 2 blocks/CU). LDS:
// double-buffered 4 static arrays = 48 KB/block (96 KB/CU for 2 blocks). Per K-tile:
// barrier / issue 6 gload_lds (next tile) / vmcnt(6) counted / barrier / 4 free phases.
__global__ __launch_bounds__(256, 2) void gemm_out(
    const __hip_bfloat16* __restrict__ A,
    const __hip_bfloat16* __restrict__ Bm,
    float* __restrict__ C,
    const float* __restrict__ bias)
{
    constexpr int K  = 1024;
    constexpr int N  = 1024;

    __shared__ short oA0[8192];   // 128 x 64 bf16 = 16 KB
    __shared__ short oB0[4096];   //  64 x 64 bf16 =  8 KB
    __shared__ short oA1[8192];
    __shared__ short oB1[4096];

    const int tid  = threadIdx.x;
    const int lane = tid & 63;
    const int wv   = tid >> 6;                 // 0..3

    const int bid    = blockIdx.x;
    const int xcd    = bid & 7;
    const int loc    = bid >> 3;               // 0..63
    const int n_tile = xcd * 2 + (loc & 1);    // 0..15
    const int m_tile = loc >> 1;               // 0..31
    const int m0 = m_tile * 128;
    const int n0 = n_tile * 64;

    const int srow   = tid >> 3;               // 0..31
    const int schunk = tid & 7;
    const int scg    = schunk ^ (srow & 7);
    const __hip_bfloat16* Ag = A  + (size_t)(m0 + srow) * K + scg * 8;
    const __hip_bfloat16* Bg = Bm + (size_t)(n0 + srow) * K + scg * 8;
    const int wvoff = wv * 1024;

    const int wrow  = wv * 32;
    const int fr    = lane & 31;
    const int khalf = lane >> 5;
    const int sw    = fr & 7;

    const int offA = (wrow + fr) * 128;
    int offB[2];
    #pragma unroll
    for (int j = 0; j < 2; ++j) offB[j] = (j * 32 + fr) * 128;
    const int swA = (wrow + fr) & 7;           // == sw (wrow%8==0) but keep explicit

    floatx16 acc[2] = {};

    // ---- prologue: stage tile 0 into buffers 0 (A: 4 segs of 32 rows, B: 2 segs) ----
    #pragma unroll
    for (int s = 0; s < 4; ++s)
        gload_lds16(Ag + (size_t)(s * 32) * K, (char*)oA0 + s * 4096 + wvoff);
    #pragma unroll
    for (int s = 0; s < 2; ++s)
        gload_lds16(Bg + (size_t)(s * 32) * K, (char*)oB0 + s * 4096 + wvoff);

#define OTILE_BODY(RA, RB, WA, WB, k_next, DO_STAGE)                                      \
    {                                                                                     \
        __builtin_amdgcn_s_barrier();                                                     \
        if (DO_STAGE) {                                                                   \
            _Pragma("unroll")                                                             \
            for (int s = 0; s < 4; ++s)                                                   \
                gload_lds16(Ag + (size_t)(s * 32) * K + (k_next),                         \
                            (char*)(WA) + s * 4096 + wvoff);                              \
            _Pragma("unroll")                                                             \
            for (int s = 0; s < 2; ++s)                                                   \
                gload_lds16(Bg + (size_t)(s * 32) * K + (k_next),                         \
                            (char*)(WB) + s * 4096 + wvoff);                              \
            asm volatile("s_waitcnt vmcnt(6)" ::: "memory");                              \
        } else {                                                                          \
            asm volatile("s_waitcnt vmcnt(0)" ::: "memory");                              \
        }                                                                                 \
        __builtin_amdgcn_s_barrier();                                                     \
        __builtin_amdgcn_sched_barrier(0);                                                \
        _Pragma("unroll")                                                                 \
        for (int kk = 0; kk < 4; ++kk) {                                                  \
            const int cg = kk * 2 + khalf;                                                \
            short8 af = *(const short8*)((const char*)(RA) + offA + ((cg ^ swA) * 16));   \
            short8 bf[2];                                                                 \
            _Pragma("unroll")                                                             \
            for (int j = 0; j < 2; ++j)                                                   \
                bf[j] = *(const short8*)((const char*)(RB) + offB[j] + ((cg ^ sw) * 16)); \
            __builtin_amdgcn_s_setprio(1);                                                \
            _Pragma("unroll")                                                             \
            for (int j = 0; j < 2; ++j)                                                   \
                acc[j] = __builtin_amdgcn_mfma_f32_32x32x16_bf16(af, bf[j], acc[j], 0, 0, 0); \
            __builtin_amdgcn_s_setprio(0);                                                \
        }                                                                                 \
    }

    #pragma unroll 1
    for (int t2 = 0; t2 < 8; ++t2) {
        OTILE_BODY(oA0, oB0, oA1, oB1, (2 * t2 + 1) * 64, true);
        OTILE_BODY(oA1, oB1, oA0, oB0, (2 * t2 + 2) * 64, (t2 < 7));
    }
#undef OTILE_BODY

    #pragma unroll
    for (int j = 0; j < 2; ++j) {
        const int col = n0 + j * 32 + fr;
        const float bb = bias[col];
        #pragma unroll
        for (int reg = 0; reg < 16; ++reg) {
            const int row = m0 + wrow + 4 * khalf + (reg & 3) + 8 * (reg >> 2);
            C[(size_t)row * N + col] = acc[j][reg] + bb;
        }
    }
}

// ---------- launch ----------
extern "C" void kernel_launch(void* const* d_in, const int* in_sizes, int n_in,
                              void* d_out, int out_size, void* d_ws, size_t ws_size,
                              hipStream_t stream) {
    const float* input_vec  = (const float*)d_in[0];
    const float* hidden_vec = (const float*)d_in[1];
    const float* cell_vec   = (const float*)d_in[2];
    const float* Wx_f = (const float*)d_in[3];
    const float* bx_f = (const float*)d_in[4];
    const float* Wh_f = (const float*)d_in[5];
    const float* Wx_i = (const float*)d_in[6];
    const float* bx_i = (const float*)d_in[7];
    const float* Wh_i = (const float*)d_in[8];
    const float* Wx_o = (const float*)d_in[9];
    const float* bx_o = (const float*)d_in[10];
    const float* Wh_o = (const float*)d_in[11];
    const float* Wx_g = (const float*)d_in[12];
    const float* bx_g = (const float*)d_in[13];
    const float* Wh_g = (const float*)d_in[14];
    const float* W_out = (const float*)d_in[15];
    const float* b_out = (const float*)d_in[16];

    char* ws = (char*)d_ws;
    __hip_bfloat16* xh  = (__hip_bfloat16*)(ws);                        // 16 MB [4096][2048]
    __hip_bfloat16* Wc  = (__hip_bfloat16*)(ws + (16ull << 20));        // 16 MB [4096][2048]
    __hip_bfloat16* Wob = (__hip_bfloat16*)(ws + (32ull << 20));        //  2 MB [1024][1024]
    __hip_bfloat16* hb  = (__hip_bfloat16*)(ws + (34ull << 20));        //  8 MB [4096][1024]

    float* new_hidden = (float*)d_out;
    float* new_cell   = new_hidden + (size_t)B_ * H_;
    float* out_vec    = new_cell + (size_t)B_ * H_;

    Ptrs8 p;
    p.p[0] = Wx_f; p.p[1] = Wh_f; p.p[2] = Wx_i; p.p[3] = Wh_i;
    p.p[4] = Wx_o; p.p[5] = Wh_o; p.p[6] = Wx_g; p.p[7] = Wh_g;
    cvt_all_kernel<<<2048, 256, 0, stream>>>(input_vec, hidden_vec, p, W_out, xh, Wc, Wob);

    // gates GEMM + fused gating: writes new_hidden, new_cell (fp32) and hb (bf16)
    gemm_gate_fused<<<256, 512, 0, stream>>>(
        xh, Wc, cell_vec, bx_f, bx_i, bx_o, bx_g, new_hidden, new_cell, hb);

    // output_vec = new_hidden @ W_out^T + b_out
    gemm_out<<<512, 256, 0, stream>>>(hb, Wob, out_vec, b_out);
}

// Round 9
// 235.546 us; speedup vs baseline: 1.0283x; 1.0221x over previous
//
#include <hip/hip_runtime.h>
#include <hip/hip_bf16.h>
#include <stdint.h>

#define B_   4096
#define IN_  1024
#define H_   1024
#define OUT_ 1024

typedef __attribute__((ext_vector_type(8)))  short short8;
typedef __attribute__((ext_vector_type(4)))  float floatx4;
typedef __attribute__((ext_vector_type(16))) float floatx16;

// ---------- async global->LDS (16B per lane; LDS base wave-uniform, HW adds lane*16) ----------
__device__ static inline void gload_lds16(const void* g, void* l) {
    __builtin_amdgcn_global_load_lds(
        (const __attribute__((address_space(1))) unsigned int*)g,
        (__attribute__((address_space(3))) unsigned int*)l,
        16, 0, 0);
}

__device__ static inline float sigmoidf_(float x) { return 1.0f / (1.0f + __expf(-x)); }
__device__ static inline float tanhf_(float x)    { return 1.0f - 2.0f / (1.0f + __expf(2.0f * x)); }

// ---------- merged conversion kernel — R12: Wc interleave period 64 (was 128) ----------
// Wc row n holds gate (n>>4)&3 of h = ((n>>6)<<4) + (n&15): 16-col gate blocks so a
// 64-col wave band in the 16x16-MFMA gate GEMM = one full gate period.
struct Ptrs8 { const float* p[8]; };

__global__ __launch_bounds__(256) void cvt_all_kernel(
        const float* __restrict__ x, const float* __restrict__ h,
        Ptrs8 ptrs, const float* __restrict__ wout,
        __hip_bfloat16* __restrict__ xh,
        __hip_bfloat16* __restrict__ Wc,
        __hip_bfloat16* __restrict__ Wob) {
    const int nth = gridDim.x * blockDim.x;
    for (int g = blockIdx.x * blockDim.x + threadIdx.x; g < 2228224; g += nth) {
        const float* src;
        __hip_bfloat16* dst;
        if (g < 1048576) {
            int b  = g >> 8;
            int c8 = (g & 255) * 8;
            src = (c8 < IN_) ? (x + (size_t)b * IN_ + c8)
                             : (h + (size_t)b * H_ + (c8 - IN_));
            dst = xh + (size_t)b * 2048 + c8;
        } else if (g < 2097152) {
            int gg = g - 1048576;
            int n  = gg >> 8;
            int c8 = (gg & 255) * 8;
            int gate = (n >> 4) & 3;
            int hh   = ((n >> 6) << 4) + (n & 15);
            src = (c8 < 1024) ? (ptrs.p[2 * gate]     + (size_t)hh * 1024 + c8)
                              : (ptrs.p[2 * gate + 1] + (size_t)hh * 1024 + (c8 - 1024));
            dst = Wc + (size_t)n * 2048 + c8;
        } else {
            int gg = g - 2097152;
            src = wout + (size_t)gg * 8;
            dst = Wob + (size_t)gg * 8;
        }
        float4 v0 = *(const float4*)src;
        float4 v1 = *(const float4*)(src + 4);
        __hip_bfloat16 tmp[8];
        tmp[0] = __float2bfloat16(v0.x);
        tmp[1] = __float2bfloat16(v0.y);
        tmp[2] = __float2bfloat16(v0.z);
        tmp[3] = __float2bfloat16(v0.w);
        tmp[4] = __float2bfloat16(v1.x);
        tmp[5] = __float2bfloat16(v1.y);
        tmp[6] = __float2bfloat16(v1.z);
        tmp[7] = __float2bfloat16(v1.w);
        *(uint4*)dst = *(const uint4*)tmp;
    }
}

// ---------- gate GEMM + fused LSTM epilogue — R12: m201 8-phase template port ----------
// 256x256 tile, BK=64, 8 waves 2M x 4N (wave = 128 rows x 64 cols), 16x16x32 MFMA,
// acc[8][4] f32x4 (128 acc regs). LDS: 8 distinct 16KB arrays (2 dbuf x {A,B} x 2
// 128-row halves) = 128 KB, 1 block/CU. Per 2-K-tile iter: 8 phases, each
// {ds_reads | stage ONE half-tile | barrier | setprio 16xMFMA setprio | [vmcnt(4)
// at P4,P8] | barrier}. Staging ledger (slot: staged-at -> read-at, retire-vmcnt):
//  B1h1: P1 -> P5/P6 (P4)   A1h1: P2 -> P5/P7 (P4)   B0h0: P3 -> +P1/P2 (P8)
//  B0h1: P4 -> +P1/P2 (P8)  A0h0: P5 -> +P1/P3 (P8)  A0h1: P6 -> +P1/P3 (P8)
//  B1h0: P7 -> +P5/P6 (+P4) A1h0: P8 -> +P5/P7 (+P4)
// vmcnt(4) keeps the newest 2 half-tiles in flight, retires everything older —
// exactly what the next 3 phases read. Tail: tiles 32,33 staged unconditionally
// (garbage, never read; addresses verified inside workspace) -> uniform 16 iters.
__global__ __launch_bounds__(512, 2) void gemm_gate_fused(
    const __hip_bfloat16* __restrict__ A,
    const __hip_bfloat16* __restrict__ Bm,
    const float* __restrict__ cell,
    const float* __restrict__ bxf, const float* __restrict__ bxi,
    const float* __restrict__ bxo, const float* __restrict__ bxg,
    float* __restrict__ new_hidden, float* __restrict__ new_cell,
    __hip_bfloat16* __restrict__ hb)
{
    constexpr int K = 2048;

    __shared__ short A0h0[8192];  // dbuf0 A rows   0..127 (even tiles)
    __shared__ short A0h1[8192];  // dbuf0 A rows 128..255
    __shared__ short B0h0[8192];  // dbuf0 B rows   0..127
    __shared__ short B0h1[8192];  // dbuf0 B rows 128..255
    __shared__ short A1h0[8192];  // dbuf1 (odd tiles)
    __shared__ short A1h1[8192];
    __shared__ short B1h0[8192];
    __shared__ short B1h1[8192];

    const int tid  = threadIdx.x;
    const int lane = tid & 63;
    const int wv   = tid >> 6;      // 0..7
    const int wm   = wv >> 2;       // 0..1: row half (128 rows)
    const int wn   = wv & 3;        // 0..3: col band (64 cols)

    // 256 blocks = 1/CU. XCD swizzle.
    const int bid    = blockIdx.x;
    const int xcd    = bid & 7;
    const int loc    = bid >> 3;
    const int n_tile = xcd * 2 + (loc & 1);
    const int m_tile = loc >> 1;
    const int m0 = m_tile * 256;
    const int n0 = n_tile * 256;

    // staging: thread tid fills LDS slot tid*16 (wave-uniform base + lane*16);
    // row = (tid>>3) + s*64 within the 128-row half; source chunk XOR-swizzled.
    const int srow   = tid >> 3;    // 0..63
    const int scg    = (tid & 7) ^ (srow & 7);
    const __hip_bfloat16* Ag = A  + (size_t)(m0 + srow) * K + scg * 8;
    const __hip_bfloat16* Bg = Bm + (size_t)(n0 + srow) * K + scg * 8;
    const int wvoff = wv * 1024;

    // fragment read addressing (16x16x32): lane l: row = base + (l&15),
    // k-bytes 16 at quarter q=(l>>4); swizzled chunk = (ks*4+q) ^ (l&7).
    const int fr16 = lane & 15;
    const int q    = lane >> 4;
    const int frb  = fr16 * 128;
    const int bb   = (wn & 1) * 8192;   // col sub-band within B half
    int ck[2];
    #pragma unroll
    for (int ks = 0; ks < 2; ++ks) ck[ks] = (((ks * 4 + q) ^ (lane & 7)) << 4);

    const short* myA0 = wm ? A0h1 : A0h0;
    const short* myA1 = wm ? A1h1 : A1h0;
    const short* myB0 = (wn >> 1) ? B0h1 : B0h0;
    const short* myB1 = (wn >> 1) ? B1h1 : B1h0;

    short8  fA[4][2];   // current M-quadrant: 4 m-frags x 2 k-slices
    short8  fB[4][2];   // all 4 n-frags x 2 k-slices (live across the tile)
    floatx4 acc[8][4] = {};

#define STG_A(DST, hh, t) do {                                                            \
    gload_lds16(Ag + (size_t)((hh)*128 +  0) * K + (size_t)(t) * 64,                      \
                (char*)(DST) + 0 * 8192 + wvoff);                                         \
    gload_lds16(Ag + (size_t)((hh)*128 + 64) * K + (size_t)(t) * 64,                      \
                (char*)(DST) + 1 * 8192 + wvoff);                                         \
} while (0)
#define STG_B(DST, hh, t) do {                                                            \
    gload_lds16(Bg + (size_t)((hh)*128 +  0) * K + (size_t)(t) * 64,                      \
                (char*)(DST) + 0 * 8192 + wvoff);                                         \
    gload_lds16(Bg + (size_t)((hh)*128 + 64) * K + (size_t)(t) * 64,                      \
                (char*)(DST) + 1 * 8192 + wvoff);                                         \
} while (0)
#define READ_A(ARR, mh) do {                                                              \
    _Pragma("unroll") for (int i = 0; i < 4; ++i)                                         \
    _Pragma("unroll") for (int ks = 0; ks < 2; ++ks)                                      \
        fA[i][ks] = *(const short8*)((const char*)(ARR) + (mh)*8192 + i*2048 + frb + ck[ks]); \
} while (0)
#define READ_B(ARR, nh) do {                                                              \
    _Pragma("unroll") for (int jj = 0; jj < 2; ++jj)                                      \
    _Pragma("unroll") for (int ks = 0; ks < 2; ++ks)                                      \
        fB[(nh)*2+jj][ks] = *(const short8*)((const char*)(ARR) + bb + ((nh)*2+jj)*2048 + frb + ck[ks]); \
} while (0)
#define MFMA_Q(mh, nh) do {                                                               \
    __builtin_amdgcn_s_setprio(1);                                                        \
    _Pragma("unroll") for (int i = 0; i < 4; ++i)                                         \
    _Pragma("unroll") for (int jj = 0; jj < 2; ++jj)                                      \
    _Pragma("unroll") for (int ks = 0; ks < 2; ++ks)                                      \
        acc[(mh)*4+i][(nh)*2+jj] = __builtin_amdgcn_mfma_f32_16x16x32_bf16(               \
            fA[i][ks], fB[(nh)*2+jj][ks], acc[(mh)*4+i][(nh)*2+jj], 0, 0, 0);             \
    __builtin_amdgcn_s_setprio(0);                                                        \
} while (0)
#define BAR __builtin_amdgcn_s_barrier()
#define VM4 asm volatile("s_waitcnt vmcnt(4)" ::: "memory")

    // ---- prologue: tile 0 (4 half-tiles) + tile 1's h0 pair; retire tile 0 ----
    STG_B(B0h0, 0, 0); STG_B(B0h1, 1, 0);
    STG_A(A0h0, 0, 0); STG_A(A0h1, 1, 0);
    STG_B(B1h0, 0, 1); STG_A(A1h0, 0, 1);
    VM4;                       // retire tile-0 half-tiles; keep B1h0,A1h0 in flight
    BAR;

    #pragma unroll 1
    for (int it = 0; it < 16; ++it) {
        const int t1 = 2 * it + 1;
        const int t2 = 2 * it + 2;   // at it=15: garbage tiles 32,33 (never read)
        const int t3 = 2 * it + 3;

        // P1
        READ_A(myA0, 0); READ_B(myB0, 0);
        STG_B(B1h1, 1, t1);
        BAR; MFMA_Q(0, 0); BAR;
        // P2
        READ_B(myB0, 1);
        STG_A(A1h1, 1, t1);
        BAR; MFMA_Q(0, 1); BAR;
        // P3
        READ_A(myA0, 1);
        STG_B(B0h0, 0, t2);
        BAR; MFMA_Q(1, 0); BAR;
        // P4
        STG_B(B0h1, 1, t2);
        BAR; MFMA_Q(1, 1); VM4; BAR;
        // P5
        READ_A(myA1, 0); READ_B(myB1, 0);
        STG_A(A0h0, 0, t2);
        BAR; MFMA_Q(0, 0); BAR;
        // P6
        READ_B(myB1, 1);
        STG_A(A0h1, 1, t2);
        BAR; MFMA_Q(0, 1); BAR;
        // P7
        READ_A(myA1, 1);
        STG_B(B1h0, 0, t3);
        BAR; MFMA_Q(1, 0); BAR;
        // P8
        STG_A(A1h0, 0, t3);
        BAR; MFMA_Q(1, 1); VM4; BAR;
    }

#undef STG_A
#undef STG_B
#undef READ_A
#undef READ_B
#undef MFMA_Q
#undef BAR
#undef VM4

    // fused LSTM epilogue. C/D 16x16 layout: col = lane&15, row = (lane>>4)*4 + reg.
    // Wave cols n0+wn*64..+64 = one gate period (16-col gate blocks) -> frag index
    // n == gate; lane owns all 4 gates of h = (n0+wn*64)/4 + (lane&15).
    const int hcol = ((n0 + wn * 64) >> 2) + fr16;
    const float bfb = bxf[hcol];
    const float bib = bxi[hcol];
    const float bob = bxo[hcol];
    const float bgb = bxg[hcol];

    #pragma unroll
    for (int m = 0; m < 8; ++m) {
        const int row_base = m0 + wm * 128 + m * 16 + q * 4;
        #pragma unroll
        for (int reg = 0; reg < 4; ++reg) {
            const int row = row_base + reg;
            const size_t off = (size_t)row * H_ + hcol;
            const float f  = sigmoidf_(acc[m][0][reg] + bfb);
            const float ii = sigmoidf_(acc[m][1][reg] + bib);
            const float o  = sigmoidf_(acc[m][2][reg] + bob);
            const float g  = tanhf_(acc[m][3][reg] + bgb);
            const float c  = f * cell[off] + ii * g;
            const float nh = o * tanhf_(c);
            new_cell[off]   = c;
            new_hidden[off] = nh;
            hb[off] = __float2bfloat16(nh);
        }
    }
}

// ---------- output GEMM (R11 pipelined version, unchanged) ----------
__global__ __launch_bounds__(256, 2) void gemm_out(
    const __hip_bfloat16* __restrict__ A,
    const __hip_bfloat16* __restrict__ Bm,
    float* __restrict__ C,
    const float* __restrict__ bias)
{
    constexpr int K  = 1024;
    constexpr int N  = 1024;

    __shared__ short oA0[8192];
    __shared__ short oB0[4096];
    __shared__ short oA1[8192];
    __shared__ short oB1[4096];

    const int tid  = threadIdx.x;
    const int lane = tid & 63;
    const int wv   = tid >> 6;

    const int bid    = blockIdx.x;
    const int xcd    = bid & 7;
    const int loc    = bid >> 3;
    const int n_tile = xcd * 2 + (loc & 1);
    const int m_tile = loc >> 1;
    const int m0 = m_tile * 128;
    const int n0 = n_tile * 64;

    const int srow   = tid >> 3;
    const int schunk = tid & 7;
    const int scg    = schunk ^ (srow & 7);
    const __hip_bfloat16* Ag = A  + (size_t)(m0 + srow) * K + scg * 8;
    const __hip_bfloat16* Bg = Bm + (size_t)(n0 + srow) * K + scg * 8;
    const int wvoff = wv * 1024;

    const int wrow  = wv * 32;
    const int fr    = lane & 31;
    const int khalf = lane >> 5;
    const int sw    = fr & 7;

    const int offA = (wrow + fr) * 128;
    int offB[2];
    #pragma unroll
    for (int j = 0; j < 2; ++j) offB[j] = (j * 32 + fr) * 128;
    const int swA = (wrow + fr) & 7;

    floatx16 acc[2] = {};

    #pragma unroll
    for (int s = 0; s < 4; ++s)
        gload_lds16(Ag + (size_t)(s * 32) * K, (char*)oA0 + s * 4096 + wvoff);
    #pragma unroll
    for (int s = 0; s < 2; ++s)
        gload_lds16(Bg + (size_t)(s * 32) * K, (char*)oB0 + s * 4096 + wvoff);

#define OTILE_BODY(RA, RB, WA, WB, k_next, DO_STAGE)                                      \
    {                                                                                     \
        __builtin_amdgcn_s_barrier();                                                     \
        if (DO_STAGE) {                                                                   \
            _Pragma("unroll")                                                             \
            for (int s = 0; s < 4; ++s)                                                   \
                gload_lds16(Ag + (size_t)(s * 32) * K + (k_next),                         \
                            (char*)(WA) + s * 4096 + wvoff);                              \
            _Pragma("unroll")                                                             \
            for (int s = 0; s < 2; ++s)                                                   \
                gload_lds16(Bg + (size_t)(s * 32) * K + (k_next),                         \
                            (char*)(WB) + s * 4096 + wvoff);                              \
            asm volatile("s_waitcnt vmcnt(6)" ::: "memory");                              \
        } else {                                                                          \
            asm volatile("s_waitcnt vmcnt(0)" ::: "memory");                              \
        }                                                                                 \
        __builtin_amdgcn_s_barrier();                                                     \
        __builtin_amdgcn_sched_barrier(0);                                                \
        _Pragma("unroll")                                                                 \
        for (int kk = 0; kk < 4; ++kk) {                                                  \
            const int cg = kk * 2 + khalf;                                                \
            short8 af = *(const short8*)((const char*)(RA) + offA + ((cg ^ swA) * 16));   \
            short8 bf[2];                                                                 \
            _Pragma("unroll")                                                             \
            for (int j = 0; j < 2; ++j)                                                   \
                bf[j] = *(const short8*)((const char*)(RB) + offB[j] + ((cg ^ sw) * 16)); \
            __builtin_amdgcn_s_setprio(1);                                                \
            _Pragma("unroll")                                                             \
            for (int j = 0; j < 2; ++j)                                                   \
                acc[j] = __builtin_amdgcn_mfma_f32_32x32x16_bf16(af, bf[j], acc[j], 0, 0, 0); \
            __builtin_amdgcn_s_setprio(0);                                                \
        }                                                                                 \
    }

    #pragma unroll 1
    for (int t2 = 0; t2 < 8; ++t2) {
        OTILE_BODY(oA0, oB0, oA1, oB1, (2 * t2 + 1) * 64, true);
        OTILE_BODY(oA1, oB1, oA0, oB0, (2 * t2 + 2) * 64, (t2 < 7));
    }
#undef OTILE_BODY

    #pragma unroll
    for (int j = 0; j < 2; ++j) {
        const int col = n0 + j * 32 + fr;
        const float bb = bias[col];
        #pragma unroll
        for (int reg = 0; reg < 16; ++reg) {
            const int row = m0 + wrow + 4 * khalf + (reg & 3) + 8 * (reg >> 2);
            C[(size_t)row * N + col] = acc[j][reg] + bb;
        }
    }
}

// ---------- launch ----------
extern "C" void kernel_launch(void* const* d_in, const int* in_sizes, int n_in,
                              void* d_out, int out_size, void* d_ws, size_t ws_size,
                              hipStream_t stream) {
    const float* input_vec  = (const float*)d_in[0];
    const float* hidden_vec = (const float*)d_in[1];
    const float* cell_vec   = (const float*)d_in[2];
    const float* Wx_f = (const float*)d_in[3];
    const float* bx_f = (const float*)d_in[4];
    const float* Wh_f = (const float*)d_in[5];
    const float* Wx_i = (const float*)d_in[6];
    const float* bx_i = (const float*)d_in[7];
    const float* Wh_i = (const float*)d_in[8];
    const float* Wx_o = (const float*)d_in[9];
    const float* bx_o = (const float*)d_in[10];
    const float* Wh_o = (const float*)d_in[11];
    const float* Wx_g = (const float*)d_in[12];
    const float* bx_g = (const float*)d_in[13];
    const float* Wh_g = (const float*)d_in[14];
    const float* W_out = (const float*)d_in[15];
    const float* b_out = (const float*)d_in[16];

    char* ws = (char*)d_ws;
    __hip_bfloat16* xh  = (__hip_bfloat16*)(ws);                        // 16 MB [4096][2048]
    __hip_bfloat16* Wc  = (__hip_bfloat16*)(ws + (16ull << 20));        // 16 MB [4096][2048]
    __hip_bfloat16* Wob = (__hip_bfloat16*)(ws + (32ull << 20));        //  2 MB [1024][1024]
    __hip_bfloat16* hb  = (__hip_bfloat16*)(ws + (34ull << 20));        //  8 MB [4096][1024]

    float* new_hidden = (float*)d_out;
    float* new_cell   = new_hidden + (size_t)B_ * H_;
    float* out_vec    = new_cell + (size_t)B_ * H_;

    Ptrs8 p;
    p.p[0] = Wx_f; p.p[1] = Wh_f; p.p[2] = Wx_i; p.p[3] = Wh_i;
    p.p[4] = Wx_o; p.p[5] = Wh_o; p.p[6] = Wx_g; p.p[7] = Wh_g;
    cvt_all_kernel<<<2048, 256, 0, stream>>>(input_vec, hidden_vec, p, W_out, xh, Wc, Wob);

    // gates GEMM + fused gating: writes new_hidden, new_cell (fp32) and hb (bf16)
    gemm_gate_fused<<<256, 512, 0, stream>>>(
        xh, Wc, cell_vec, bx_f, bx_i, bx_o, bx_g, new_hidden, new_cell, hb);

    // output_vec = new_hidden @ W_out^T + b_out
    gemm_out<<<512, 256, 0, stream>>>(hb, Wob, out_vec, b_out);
}